// Round 4
// 6575.383 us; speedup vs baseline: 1.0312x; 1.0312x over previous
//
#include <hip/hip_runtime.h>
#include <stdint.h>

#define NSAMP 400
#define NC 512

#if __has_builtin(__builtin_amdgcn_exp2f)
#define EXP2F(x) __builtin_amdgcn_exp2f(x)
#else
#define EXP2F(x) __expf((x) * 0.6931471805599453f)
#endif
#if __has_builtin(__builtin_amdgcn_logf)
#define LOG2F(x) __builtin_amdgcn_logf(x)
#else
#define LOG2F(x) (__logf(x) * 1.4426950408889634f)
#endif

static __device__ __forceinline__ uint32_t rotl32(uint32_t v, int n) {
  return (v << n) | (v >> (32 - n));
}

// Full threefry2x32 (setup only).
#define TFS(x0, x1, R) { x0 += x1; x1 = rotl32(x1, R); x1 ^= x0; }
static __device__ __forceinline__ void threefry2x32_full(
    uint32_t k0, uint32_t k1, uint32_t x0, uint32_t x1,
    uint32_t& o0, uint32_t& o1)
{
  const uint32_t ks2 = k0 ^ k1 ^ 0x1BD11BDAu;
  x0 += k0; x1 += k1;
  TFS(x0,x1,13) TFS(x0,x1,15) TFS(x0,x1,26) TFS(x0,x1, 6)
  x0 += k1; x1 += ks2 + 1u;
  TFS(x0,x1,17) TFS(x0,x1,29) TFS(x0,x1,16) TFS(x0,x1,24)
  x0 += ks2; x1 += k0 + 2u;
  TFS(x0,x1,13) TFS(x0,x1,15) TFS(x0,x1,26) TFS(x0,x1, 6)
  x0 += k0; x1 += k1 + 3u;
  TFS(x0,x1,17) TFS(x0,x1,29) TFS(x0,x1,16) TFS(x0,x1,24)
  x0 += k1; x1 += ks2 + 4u;
  TFS(x0,x1,13) TFS(x0,x1,15) TFS(x0,x1,26) TFS(x0,x1, 6)
  x0 += ks2; x1 += k0 + 5u;
  o0 = x0; o1 = x1;
}

// ---------------------------------------------------------------------------
// JAX *partitionable* threefry per element: bits(i) = x0f ^ x1f of
// cipher(key_s, data=(0, i)).  Verified bit-exact vs the reference in the
// round-0 run (absmax 6.1e-5 = ulp level).  Op-minimized, stream-identical:
//  - round-1 add folded into init
//  - injections 1-4 fused with the next round's add (v_add3_u32)
// ---------------------------------------------------------------------------
#define R3OP(R)          { x0 += x1; x1 = rotl32(x1, R) ^ x0; }
#define INJR(ka, kb, R)  { x1 += kb; x0 = x0 + x1 + ka; x1 = rotl32(x1, R) ^ x0; }

static __device__ __forceinline__ uint32_t tf_bits_fused(
    uint32_t k0, uint32_t k1, uint32_t ks2,
    uint32_t I1, uint32_t I2, uint32_t I3, uint32_t I4, uint32_t I5,
    uint32_t cnt)
{
  uint32_t x1 = cnt + k1;
  uint32_t x0 = x1 + k0;              // == x0_init(k0) + x1  (round-1 add)
  x1 = rotl32(x1, 13) ^ x0;           // round 1 tail
  R3OP(15) R3OP(26) R3OP(6)
  INJR(k1,  I1, 17) R3OP(29) R3OP(16) R3OP(24)
  INJR(ks2, I2, 13) R3OP(15) R3OP(26) R3OP(6)
  INJR(k0,  I3, 17) R3OP(29) R3OP(16) R3OP(24)
  INJR(k1,  I4, 13) R3OP(15) R3OP(26) R3OP(6)
  x0 += ks2; x1 += I5;                // final injection
  return x0 ^ x1;                     // JAX partitionable 32-bit fold
}

// bits -> u in [-0.99999994, 1) (bit-exact JAX uniform) -> L = log2(1-u^2)
static __device__ __forceinline__ void bits2uL(uint32_t bits, float& u, float& L) {
  float f = __uint_as_float(__builtin_amdgcn_alignbit(0x7Fu, bits, 9u)) - 1.0f;
  u = fmaf(f, 2.0f, -0.99999994f);     // max(lo,.) provably identity
  L = LOG2F(fmaf(u, -u, 1.0f));
}

// erfinv (Giles/XLA coefficients) on log2 basis fused with exp2.
static __device__ __forceinline__ float softexp(float u, float L, float sd2, float m2) {
  float p;
  if (L > -7.2134752f) {                    // central branch
    float w = fmaf(L, -0.69314718f, -2.5f);
    p =              2.81022636e-08f;
    p = fmaf(p, w,   3.43273939e-07f);
    p = fmaf(p, w,  -3.5233877e-06f);
    p = fmaf(p, w,  -4.39150654e-06f);
    p = fmaf(p, w,   0.00021858087f);
    p = fmaf(p, w,  -0.00125372503f);
    p = fmaf(p, w,  -0.00417768164f);
    p = fmaf(p, w,   0.246640727f);
    p = fmaf(p, w,   1.50140941f);
  } else {                                   // tail, ~0.34%/lane
    float w = __builtin_amdgcn_sqrtf(L * -0.69314718f) - 3.0f;
    p =             -0.000200214257f;
    p = fmaf(p, w,   0.000100950558f);
    p = fmaf(p, w,   0.00134934322f);
    p = fmaf(p, w,  -0.00367342844f);
    p = fmaf(p, w,   0.00573950773f);
    p = fmaf(p, w,  -0.0076224613f);
    p = fmaf(p, w,   0.00943887047f);
    p = fmaf(p, w,   1.00167406f);
    p = fmaf(p, w,   2.83297682f);
  }
  float px = p * u;
  return EXP2F(fmaf(px, sd2, m2));
}

static __device__ __forceinline__ uint32_t rfl(uint32_t x) {
  return (uint32_t)__builtin_amdgcn_readfirstlane((int)x);
}

// Wave64 sum via DPP (row_shr 1/2/4/8, row_bcast 15/31), total in lane 63,
// broadcast back through readlane.  No LDS traffic, short serial chain.
// dpp_ctrl must be an integer constant expression -> template parameter.
template <int CTRL>
static __device__ __forceinline__ float dppadd(float x) {
  return x + __int_as_float(
      __builtin_amdgcn_update_dpp(0, __float_as_int(x), CTRL, 0xf, 0xf, false));
}
static __device__ __forceinline__ float wave_sum_bcast(float x) {
  x = dppadd<0x111>(x);   // row_shr:1
  x = dppadd<0x112>(x);   // row_shr:2
  x = dppadd<0x114>(x);   // row_shr:4
  x = dppadd<0x118>(x);   // row_shr:8
  x = dppadd<0x142>(x);   // row_bcast:15
  x = dppadd<0x143>(x);   // row_bcast:31
  return __uint_as_float((uint32_t)__builtin_amdgcn_readlane(__float_as_int(x), 63));
}

// One wave per row; 8 columns per lane; 4 waves/block.  Sample loop unrolled
// x2: sample A's reduce/acc tail is scheduled inside sample B's branch-free
// cipher region.
__global__ __launch_bounds__(256)
void mc_softmax_kernel(const float* __restrict__ mean,
                       const float* __restrict__ var,
                       float* __restrict__ out)
{
  // Per-sample constant table (JAX fold-like split: key_s = both words of
  // cipher((0,42),(0,s)) — verified bit-exact in round 0):
  // [s] = {k0, k1, ks2, ks2+1, k0+2, k1+3, ks2+4, k0+5}
  __shared__ __align__(16) uint32_t kc[NSAMP][8];
  for (int s = threadIdx.x; s < NSAMP; s += 256) {
    uint32_t a, b;
    threefry2x32_full(0u, 42u, 0u, (uint32_t)s, a, b);
    uint32_t ks2 = a ^ b ^ 0x1BD11BDAu;
    kc[s][0] = a;        kc[s][1] = b;
    kc[s][2] = ks2;      kc[s][3] = ks2 + 1u;
    kc[s][4] = a + 2u;   kc[s][5] = b + 3u;
    kc[s][6] = ks2 + 4u; kc[s][7] = a + 5u;
  }
  __syncthreads();

  const int lane  = threadIdx.x & 63;
  const int row   = (blockIdx.x << 2) + (threadIdx.x >> 6);
  const int cbase = lane << 2;

  const float* mr = mean + (size_t)row * NC;
  const float* vr = var  + (size_t)row * NC;

  float m2[8], sd2[8], acc[8];
  {
    const float L2E = 1.4426950408889634f;   // log2(e)
    const float S2L = 2.0402788959f;         // sqrt(2)*log2(e)
    float4 t0 = *(const float4*)(mr + cbase);
    float4 t1 = *(const float4*)(mr + 256 + cbase);
    m2[0] = t0.x * L2E; m2[1] = t0.y * L2E; m2[2] = t0.z * L2E; m2[3] = t0.w * L2E;
    m2[4] = t1.x * L2E; m2[5] = t1.y * L2E; m2[6] = t1.z * L2E; m2[7] = t1.w * L2E;
    float4 v0 = *(const float4*)(vr + cbase);
    float4 v1 = *(const float4*)(vr + 256 + cbase);
    sd2[0] = __builtin_amdgcn_sqrtf(v0.x) * S2L;
    sd2[1] = __builtin_amdgcn_sqrtf(v0.y) * S2L;
    sd2[2] = __builtin_amdgcn_sqrtf(v0.z) * S2L;
    sd2[3] = __builtin_amdgcn_sqrtf(v0.w) * S2L;
    sd2[4] = __builtin_amdgcn_sqrtf(v1.x) * S2L;
    sd2[5] = __builtin_amdgcn_sqrtf(v1.y) * S2L;
    sd2[6] = __builtin_amdgcn_sqrtf(v1.z) * S2L;
    sd2[7] = __builtin_amdgcn_sqrtf(v1.w) * S2L;
  }
#pragma unroll
  for (int j = 0; j < 8; ++j) acc[j] = 0.0f;

  const uint32_t base = (uint32_t)(row * NC + cbase);
  uint32_t cnt[8];
#pragma unroll
  for (int j = 0; j < 4; ++j) { cnt[j] = base + (uint32_t)j; cnt[4+j] = base + 256u + (uint32_t)j; }

  for (int s = 0; s < NSAMP; s += 2) {
    // kc rows for samples s (A) and s+1 (B); wave-uniform -> scalarize.
    const uint4 a0 = *(const uint4*)&kc[s][0];
    const uint4 a1 = *(const uint4*)&kc[s][4];
    const uint4 b0 = *(const uint4*)&kc[s + 1][0];
    const uint4 b1 = *(const uint4*)&kc[s + 1][4];
    const uint32_t Ak0 = rfl(a0.x), Ak1 = rfl(a0.y), Aks = rfl(a0.z), AI1 = rfl(a0.w);
    const uint32_t AI2 = rfl(a1.x), AI3 = rfl(a1.y), AI4 = rfl(a1.z), AI5 = rfl(a1.w);
    const uint32_t Bk0 = rfl(b0.x), Bk1 = rfl(b0.y), Bks = rfl(b0.z), BI1 = rfl(b0.w);
    const uint32_t BI2 = rfl(b1.x), BI3 = rfl(b1.y), BI4 = rfl(b1.z), BI5 = rfl(b1.w);

    // ---- A phase 1: 8 independent cipher -> u -> log chains (branch-free)
    float uA[8], LA[8];
#pragma unroll
    for (int j = 0; j < 8; ++j) {
      uint32_t bits = tf_bits_fused(Ak0, Ak1, Aks, AI1, AI2, AI3, AI4, AI5, cnt[j]);
      bits2uL(bits, uA[j], LA[j]);
    }
    // ---- A phase 2: branchy erfinv-poly + exp2
    float eA[8], sA = 0.0f;
#pragma unroll
    for (int j = 0; j < 8; ++j) { eA[j] = softexp(uA[j], LA[j], sd2[j], m2[j]); sA += eA[j]; }

    // ---- B phase 1 (branch-free region; A's reduction scheduled into it)
    float uB[8], LB[8];
#pragma unroll
    for (int j = 0; j < 8; ++j) {
      uint32_t bits = tf_bits_fused(Bk0, Bk1, Bks, BI1, BI2, BI3, BI4, BI5, cnt[j]);
      bits2uL(bits, uB[j], LB[j]);
    }

    // ---- A reduce + accumulate (overlaps with B phase 1 chains)
    const float invA = __builtin_amdgcn_rcpf(wave_sum_bcast(sA));
#pragma unroll
    for (int j = 0; j < 8; ++j) acc[j] = fmaf(eA[j], invA, acc[j]);

    // ---- B phase 2
    float eB[8], sB = 0.0f;
#pragma unroll
    for (int j = 0; j < 8; ++j) { eB[j] = softexp(uB[j], LB[j], sd2[j], m2[j]); sB += eB[j]; }

    // ---- B reduce + accumulate
    const float invB = __builtin_amdgcn_rcpf(wave_sum_bcast(sB));
#pragma unroll
    for (int j = 0; j < 8; ++j) acc[j] = fmaf(eB[j], invB, acc[j]);
  }

  float* orow = out + (size_t)row * NC;
  const float sc = 1.0f / (float)NSAMP;
  float4 o0, o1;
  o0.x = acc[0] * sc; o0.y = acc[1] * sc; o0.z = acc[2] * sc; o0.w = acc[3] * sc;
  o1.x = acc[4] * sc; o1.y = acc[5] * sc; o1.z = acc[6] * sc; o1.w = acc[7] * sc;
  *(float4*)(orow + cbase)       = o0;
  *(float4*)(orow + 256 + cbase) = o1;
}

extern "C" void kernel_launch(void* const* d_in, const int* in_sizes, int n_in,
                              void* d_out, int out_size, void* d_ws, size_t ws_size,
                              hipStream_t stream) {
  const float* mean = (const float*)d_in[0];
  const float* var  = (const float*)d_in[1];
  float* out        = (float*)d_out;

  const int rows = out_size / NC;        // 16384
  const int blocks = rows / 4;           // 4 rows (waves) per 256-thread block
  mc_softmax_kernel<<<blocks, 256, 0, stream>>>(mean, var, out);
}